// Round 8
// baseline (114.843 us; speedup 1.0000x reference)
//
#include <hip/hip_runtime.h>

// Double-sparse matvec: y = A @ (B @ x), ELL form.
// M=N=K=8192, NNZ=256 per row, BATCH=32, fp32 in/out.
//
// Cost model (R4-R7 evidence): gather cost ~ distinct 64B lines touched
// (2.1M/stage, algorithmically fixed; zero reuse per CU), plus gather
// instruction issue (16/row = byte floor at 16B/lane), plus soft terms.
// R8 polishes the soft terms:
//   - nt gathers: no reuse -> don't allocate/thrash L1
//   - all idx/vals prefetched up front -> 16 gathers in flight per wave
//   - packed-fp16 reduction tree: 4 dword shuffles + v_pk_add_f16 per step
//
// Stage 0: x16 = (fp16)x                                   -> ws + 512K
// Stage 1: bx16[k][b] = sum_j b_vals[k][j] * x16[b_idx[k][j]][b] -> ws
// Stage 2: out[b*M+m] = sum_j a_vals[m][j] * bx16[a_idx[m][j]][b]
//
// Lane layout: lane = q*4 + s.
//   s in [0,4): batch octet — 8 fp16 batch columns [8s, 8s+8) per lane
//   q in [0,16): owns consecutive nnz block j = q*16 .. q*16+15

#define NNZ    256
#define BATCH  32
#define ROWS   8192

typedef int      vi4 __attribute__((ext_vector_type(4)));
typedef float    vf4 __attribute__((ext_vector_type(4)));
typedef _Float16 vh4 __attribute__((ext_vector_type(4)));
typedef _Float16 vh8 __attribute__((ext_vector_type(8)));
typedef int      vi4u __attribute__((ext_vector_type(4)));

// ---- Stage 0: fp32 -> fp16 convert of x ([ROWS][BATCH], 256K elems) ----
__global__ __launch_bounds__(256) void cvt_f32_f16(
    const float* __restrict__ src, _Float16* __restrict__ dst)
{
    const int i = blockIdx.x * 256 + threadIdx.x;   // 4 elems per thread
    const vf4 v = *(const vf4*)(src + i * 4);
    vh4 h;
    h.x = (_Float16)v.x; h.y = (_Float16)v.y;
    h.z = (_Float16)v.z; h.w = (_Float16)v.w;
    *(vh4*)(dst + i * 4) = h;
}

// ---- Stages 1/2: ELL spmv, fp16 gathers, packed-fp16 math ----
template <bool OUT16>
__global__ __launch_bounds__(256) void ell_spmv_h(
    const int*      __restrict__ idx,   // [ROWS, NNZ]
    const float*    __restrict__ vals,  // [ROWS, NNZ]
    const _Float16* __restrict__ src,   // [src_rows, BATCH] fp16
    _Float16*       __restrict__ dst16, // [ROWS, BATCH] fp16   (OUT16)
    float*          __restrict__ dst32) // [BATCH, ROWS] fp32   (!OUT16)
{
    __shared__ float tile[4][BATCH];            // only used when !OUT16

    const int wave = threadIdx.x >> 6;          // 0..3
    const int lane = threadIdx.x & 63;
    const int r    = blockIdx.x * 4 + wave;     // sparse row
    const int s    = lane & 3;                  // batch octet id
    const int q    = lane >> 2;                 // consecutive nnz block of 16

    const vi4* i4 = (const vi4*)(idx  + r * NNZ) + q * 4;
    const vf4* v4 = (const vf4*)(vals + r * NNZ) + q * 4;
    const int  soff = s * 8;

    // Prefetch the lane's full 16 indices + 16 vals (8 VMEM instrs, then
    // all 16 gathers can be in flight together -> max MLP per wave).
    vi4 iv[4]; vf4 vv[4];
    #pragma unroll
    for (int t = 0; t < 4; ++t) iv[t] = __builtin_nontemporal_load(i4 + t);
    #pragma unroll
    for (int t = 0; t < 4; ++t) vv[t] = __builtin_nontemporal_load(v4 + t);

    vh8 acc = {0, 0, 0, 0, 0, 0, 0, 0};        // fp16 packed accumulators

    #pragma unroll
    for (int t = 0; t < 4; ++t) {
        const _Float16 h0 = (_Float16)vv[t].x, h1 = (_Float16)vv[t].y;
        const _Float16 h2 = (_Float16)vv[t].z, h3 = (_Float16)vv[t].w;
        {
            const vh8 xv = __builtin_nontemporal_load(
                (const vh8*)(src + iv[t].x * BATCH + soff));  // 16B nt gather
            const vh8 b = {h0, h0, h0, h0, h0, h0, h0, h0};
            acc += b * xv;                       // 4x v_pk_fma_f16
        }
        {
            const vh8 xv = __builtin_nontemporal_load(
                (const vh8*)(src + iv[t].y * BATCH + soff));
            const vh8 b = {h1, h1, h1, h1, h1, h1, h1, h1};
            acc += b * xv;
        }
        {
            const vh8 xv = __builtin_nontemporal_load(
                (const vh8*)(src + iv[t].z * BATCH + soff));
            const vh8 b = {h2, h2, h2, h2, h2, h2, h2, h2};
            acc += b * xv;
        }
        {
            const vh8 xv = __builtin_nontemporal_load(
                (const vh8*)(src + iv[t].w * BATCH + soff));
            const vh8 b = {h3, h3, h3, h3, h3, h3, h3, h3};
            acc += b * xv;
        }
    }

    // Packed-fp16 reduction across the 16 q-blocks: shuffle 4 dwords,
    // v_pk_add_f16 — half the ops of the fp32 version.
    #pragma unroll
    for (int d = 4; d < 64; d <<= 1) {
        union { vh8 h; vi4u i; } cur, oth;
        cur.h = acc;
        #pragma unroll
        for (int j = 0; j < 4; ++j) oth.i[j] = __shfl_xor(cur.i[j], d);
        acc += oth.h;                            // 4x v_pk_add_f16
    }

    if (OUT16) {
        if (q == 0)                              // lanes 0..3: 64B coalesced
            __builtin_nontemporal_store(acc, (vh8*)(dst16 + r * BATCH + soff));
    } else {
        if (q == 0) {
            #pragma unroll
            for (int j = 0; j < 8; ++j) tile[wave][soff + j] = (float)acc[j];
        }
        __syncthreads();
        // out[b*ROWS + r0 + rr]: 16B-contiguous segments per batch row
        const int t = threadIdx.x;
        if (t < 4 * BATCH) {
            const int b  = t >> 2;
            const int rr = t & 3;
            __builtin_nontemporal_store(tile[rr][b],
                                        dst32 + b * ROWS + blockIdx.x * 4 + rr);
        }
    }
}

extern "C" void kernel_launch(void* const* d_in, const int* in_sizes, int n_in,
                              void* d_out, int out_size, void* d_ws, size_t ws_size,
                              hipStream_t stream) {
    // setup_inputs order: x, a_idx, a_vals, b_idx, b_vals
    const float* x      = (const float*)d_in[0];   // [N, BATCH]
    const int*   a_idx  = (const int*)  d_in[1];   // [M, NNZ]
    const float* a_vals = (const float*)d_in[2];   // [M, NNZ]
    const int*   b_idx  = (const int*)  d_in[3];   // [K, NNZ]
    const float* b_vals = (const float*)d_in[4];   // [K, NNZ]
    float*       out    = (float*)d_out;           // [BATCH, M] fp32

    _Float16* bx16 = (_Float16*)d_ws;                        // 512 KB
    _Float16* x16  = (_Float16*)d_ws + (size_t)ROWS * BATCH; // 512 KB

    dim3 block(256);

    // Stage 0: convert x to fp16 (262144 elems, 4/thread)
    cvt_f32_f16<<<dim3(ROWS * BATCH / 4 / 256), block, 0, stream>>>(x, x16);
    // Stage 1: bx16 = B @ x
    ell_spmv_h<true ><<<dim3(ROWS / 4), block, 0, stream>>>(
        b_idx, b_vals, x16, bx16, nullptr);
    // Stage 2: out = A @ bx (transposed store)
    ell_spmv_h<false><<<dim3(ROWS / 4), block, 0, stream>>>(
        a_idx, a_vals, bx16, nullptr, out);
}

// Round 9
// 110.430 us; speedup vs baseline: 1.0400x; 1.0400x over previous
//
#include <hip/hip_runtime.h>

// Double-sparse matvec: y = A @ (B @ x), ELL form.
// M=N=K=8192, NNZ=256 per row, BATCH=32, fp32 in/out.
//
// R9 = exact revert to R7 (best: 110.2 us). R8's nt-hint on the gathers
// regressed +4.6 us: x16/bx16 (512 KB) live in L2 with ~32 touches/line/XCD;
// nt bypassed that reuse. nt stays ONLY on the idx/vals streams (touched
// once). Gather shape is at its floor: 16 instrs/row = 16 KB/row at the
// 16 B/lane max width; packed-fp16 FMA = 4 VALU ops/index.
//
// Stage 0: x16 = (fp16)x                                   -> ws + 512K
// Stage 1: bx16[k][b] = sum_j b_vals[k][j] * x16[b_idx[k][j]][b] -> ws
// Stage 2: out[b*M+m] = sum_j a_vals[m][j] * bx16[a_idx[m][j]][b]
//
// Lane layout: lane = q*4 + s.
//   s in [0,4): batch octet — 8 fp16 batch columns [8s, 8s+8) per lane
//   q in [0,16): owns consecutive nnz block j = q*16 .. q*16+15

#define NNZ    256
#define BATCH  32
#define ROWS   8192

typedef int      vi4 __attribute__((ext_vector_type(4)));
typedef float    vf4 __attribute__((ext_vector_type(4)));
typedef _Float16 vh4 __attribute__((ext_vector_type(4)));
typedef _Float16 vh8 __attribute__((ext_vector_type(8)));

// ---- Stage 0: fp32 -> fp16 convert of x ([ROWS][BATCH], 256K elems) ----
__global__ __launch_bounds__(256) void cvt_f32_f16(
    const float* __restrict__ src, _Float16* __restrict__ dst)
{
    const int i = blockIdx.x * 256 + threadIdx.x;   // 4 elems per thread
    const vf4 v = *(const vf4*)(src + i * 4);
    vh4 h;
    h.x = (_Float16)v.x; h.y = (_Float16)v.y;
    h.z = (_Float16)v.z; h.w = (_Float16)v.w;
    *(vh4*)(dst + i * 4) = h;
}

// ---- Stages 1/2: ELL spmv, fp16 gathers, packed-fp16 accumulate ----
template <bool OUT16>
__global__ __launch_bounds__(256) void ell_spmv_h(
    const int*      __restrict__ idx,   // [ROWS, NNZ]
    const float*    __restrict__ vals,  // [ROWS, NNZ]
    const _Float16* __restrict__ src,   // [src_rows, BATCH] fp16
    _Float16*       __restrict__ dst16, // [ROWS, BATCH] fp16   (OUT16)
    float*          __restrict__ dst32) // [BATCH, ROWS] fp32   (!OUT16)
{
    __shared__ float tile[4][BATCH];            // only used when !OUT16

    const int wave = threadIdx.x >> 6;          // 0..3
    const int lane = threadIdx.x & 63;
    const int r    = blockIdx.x * 4 + wave;     // sparse row
    const int s    = lane & 3;                  // batch octet id
    const int q    = lane >> 2;                 // consecutive nnz block of 16

    const vi4* i4 = (const vi4*)(idx  + r * NNZ) + q * 4;
    const vf4* v4 = (const vf4*)(vals + r * NNZ) + q * 4;
    const int  soff = s * 8;

    vh8 acc = {0, 0, 0, 0, 0, 0, 0, 0};        // fp16 packed accumulators

    #pragma unroll
    for (int t = 0; t < 4; ++t) {
        const vi4 iv = __builtin_nontemporal_load(i4 + t);   // lane-owned idx
        const vf4 vv = __builtin_nontemporal_load(v4 + t);
        const _Float16 h0 = (_Float16)vv.x, h1 = (_Float16)vv.y;
        const _Float16 h2 = (_Float16)vv.z, h3 = (_Float16)vv.w;
        {
            const vh8 xv = *(const vh8*)(src + iv.x * BATCH + soff);  // 16B gather, cached
            const vh8 b = {h0, h0, h0, h0, h0, h0, h0, h0};
            acc += b * xv;                       // 4x v_pk_fma_f16
        }
        {
            const vh8 xv = *(const vh8*)(src + iv.y * BATCH + soff);
            const vh8 b = {h1, h1, h1, h1, h1, h1, h1, h1};
            acc += b * xv;
        }
        {
            const vh8 xv = *(const vh8*)(src + iv.z * BATCH + soff);
            const vh8 b = {h2, h2, h2, h2, h2, h2, h2, h2};
            acc += b * xv;
        }
        {
            const vh8 xv = *(const vh8*)(src + iv.w * BATCH + soff);
            const vh8 b = {h3, h3, h3, h3, h3, h3, h3, h3};
            acc += b * xv;
        }
    }

    // widen to fp32, then reduce across the 16 q-blocks: xor 4, 8, 16, 32
    float a32[8];
    #pragma unroll
    for (int j = 0; j < 8; ++j) a32[j] = (float)acc[j];

    #pragma unroll
    for (int d = 4; d < 64; d <<= 1) {
        #pragma unroll
        for (int j = 0; j < 8; ++j) a32[j] += __shfl_xor(a32[j], d);
    }

    if (OUT16) {
        if (q == 0) {                               // lanes 0..3: 64B coalesced
            vh8 h;
            #pragma unroll
            for (int j = 0; j < 8; ++j) h[j] = (_Float16)a32[j];
            *(vh8*)(dst16 + r * BATCH + soff) = h;
        }
    } else {
        if (q == 0) {
            #pragma unroll
            for (int j = 0; j < 8; ++j) tile[wave][soff + j] = a32[j];
        }
        __syncthreads();
        // out[b*ROWS + r0 + rr]: 16B-contiguous segments per batch row
        const int t = threadIdx.x;
        if (t < 4 * BATCH) {
            const int b  = t >> 2;
            const int rr = t & 3;
            __builtin_nontemporal_store(tile[rr][b],
                                        dst32 + b * ROWS + blockIdx.x * 4 + rr);
        }
    }
}

extern "C" void kernel_launch(void* const* d_in, const int* in_sizes, int n_in,
                              void* d_out, int out_size, void* d_ws, size_t ws_size,
                              hipStream_t stream) {
    // setup_inputs order: x, a_idx, a_vals, b_idx, b_vals
    const float* x      = (const float*)d_in[0];   // [N, BATCH]
    const int*   a_idx  = (const int*)  d_in[1];   // [M, NNZ]
    const float* a_vals = (const float*)d_in[2];   // [M, NNZ]
    const int*   b_idx  = (const int*)  d_in[3];   // [K, NNZ]
    const float* b_vals = (const float*)d_in[4];   // [K, NNZ]
    float*       out    = (float*)d_out;           // [BATCH, M] fp32

    _Float16* bx16 = (_Float16*)d_ws;                        // 512 KB
    _Float16* x16  = (_Float16*)d_ws + (size_t)ROWS * BATCH; // 512 KB

    dim3 block(256);

    // Stage 0: convert x to fp16 (262144 elems, 4/thread)
    cvt_f32_f16<<<dim3(ROWS * BATCH / 4 / 256), block, 0, stream>>>(x, x16);
    // Stage 1: bx16 = B @ x
    ell_spmv_h<true ><<<dim3(ROWS / 4), block, 0, stream>>>(
        b_idx, b_vals, x16, bx16, nullptr);
    // Stage 2: out = A @ bx (transposed store)
    ell_spmv_h<false><<<dim3(ROWS / 4), block, 0, stream>>>(
        a_idx, a_vals, bx16, nullptr, out);
}

// Round 10
// 109.923 us; speedup vs baseline: 1.0448x; 1.0046x over previous
//
#include <hip/hip_runtime.h>

// Double-sparse matvec: y = A @ (B @ x), ELL form.
// M=N=K=8192, NNZ=256 per row, BATCH=32, fp32 in/out.
//
// R10 = R9 (best: 110.4 us) + ONE change: up-front prefetch of the lane's
// idx/vals vectors, so all 16 gathers can be in flight per wave (R8 bundled
// this with the bad nt-gather hint; this isolates it). Gathers stay CACHED
// (x16/bx16 are L2-resident, ~32 touches/line/XCD); nt only on idx/vals
// streams (touched once).
//
// Stage 0: x16 = (fp16)x                                   -> ws + 512K
// Stage 1: bx16[k][b] = sum_j b_vals[k][j] * x16[b_idx[k][j]][b] -> ws
// Stage 2: out[b*M+m] = sum_j a_vals[m][j] * bx16[a_idx[m][j]][b]
//
// Lane layout: lane = q*4 + s.
//   s in [0,4): batch octet — 8 fp16 batch columns [8s, 8s+8) per lane
//   q in [0,16): owns consecutive nnz block j = q*16 .. q*16+15

#define NNZ    256
#define BATCH  32
#define ROWS   8192

typedef int      vi4 __attribute__((ext_vector_type(4)));
typedef float    vf4 __attribute__((ext_vector_type(4)));
typedef _Float16 vh4 __attribute__((ext_vector_type(4)));
typedef _Float16 vh8 __attribute__((ext_vector_type(8)));

// ---- Stage 0: fp32 -> fp16 convert of x ([ROWS][BATCH], 256K elems) ----
__global__ __launch_bounds__(256) void cvt_f32_f16(
    const float* __restrict__ src, _Float16* __restrict__ dst)
{
    const int i = blockIdx.x * 256 + threadIdx.x;   // 4 elems per thread
    const vf4 v = *(const vf4*)(src + i * 4);
    vh4 h;
    h.x = (_Float16)v.x; h.y = (_Float16)v.y;
    h.z = (_Float16)v.z; h.w = (_Float16)v.w;
    *(vh4*)(dst + i * 4) = h;
}

// ---- Stages 1/2: ELL spmv, fp16 gathers, packed-fp16 accumulate ----
template <bool OUT16>
__global__ __launch_bounds__(256) void ell_spmv_h(
    const int*      __restrict__ idx,   // [ROWS, NNZ]
    const float*    __restrict__ vals,  // [ROWS, NNZ]
    const _Float16* __restrict__ src,   // [src_rows, BATCH] fp16
    _Float16*       __restrict__ dst16, // [ROWS, BATCH] fp16   (OUT16)
    float*          __restrict__ dst32) // [BATCH, ROWS] fp32   (!OUT16)
{
    __shared__ float tile[4][BATCH];            // only used when !OUT16

    const int wave = threadIdx.x >> 6;          // 0..3
    const int lane = threadIdx.x & 63;
    const int r    = blockIdx.x * 4 + wave;     // sparse row
    const int s    = lane & 3;                  // batch octet id
    const int q    = lane >> 2;                 // consecutive nnz block of 16

    const vi4* i4 = (const vi4*)(idx  + r * NNZ) + q * 4;
    const vf4* v4 = (const vf4*)(vals + r * NNZ) + q * 4;
    const int  soff = s * 8;

    // Up-front prefetch: 8 VMEM instrs, then all 16 gathers are independent.
    vi4 iv[4]; vf4 vv[4];
    #pragma unroll
    for (int t = 0; t < 4; ++t) iv[t] = __builtin_nontemporal_load(i4 + t);
    #pragma unroll
    for (int t = 0; t < 4; ++t) vv[t] = __builtin_nontemporal_load(v4 + t);

    vh8 acc = {0, 0, 0, 0, 0, 0, 0, 0};        // fp16 packed accumulators

    #pragma unroll
    for (int t = 0; t < 4; ++t) {
        const _Float16 h0 = (_Float16)vv[t].x, h1 = (_Float16)vv[t].y;
        const _Float16 h2 = (_Float16)vv[t].z, h3 = (_Float16)vv[t].w;
        {
            const vh8 xv = *(const vh8*)(src + iv[t].x * BATCH + soff);  // cached
            const vh8 b = {h0, h0, h0, h0, h0, h0, h0, h0};
            acc += b * xv;                       // 4x v_pk_fma_f16
        }
        {
            const vh8 xv = *(const vh8*)(src + iv[t].y * BATCH + soff);
            const vh8 b = {h1, h1, h1, h1, h1, h1, h1, h1};
            acc += b * xv;
        }
        {
            const vh8 xv = *(const vh8*)(src + iv[t].z * BATCH + soff);
            const vh8 b = {h2, h2, h2, h2, h2, h2, h2, h2};
            acc += b * xv;
        }
        {
            const vh8 xv = *(const vh8*)(src + iv[t].w * BATCH + soff);
            const vh8 b = {h3, h3, h3, h3, h3, h3, h3, h3};
            acc += b * xv;
        }
    }

    // widen to fp32, then reduce across the 16 q-blocks: xor 4, 8, 16, 32
    float a32[8];
    #pragma unroll
    for (int j = 0; j < 8; ++j) a32[j] = (float)acc[j];

    #pragma unroll
    for (int d = 4; d < 64; d <<= 1) {
        #pragma unroll
        for (int j = 0; j < 8; ++j) a32[j] += __shfl_xor(a32[j], d);
    }

    if (OUT16) {
        if (q == 0) {                               // lanes 0..3: 64B coalesced
            vh8 h;
            #pragma unroll
            for (int j = 0; j < 8; ++j) h[j] = (_Float16)a32[j];
            *(vh8*)(dst16 + r * BATCH + soff) = h;
        }
    } else {
        if (q == 0) {
            #pragma unroll
            for (int j = 0; j < 8; ++j) tile[wave][soff + j] = a32[j];
        }
        __syncthreads();
        // out[b*ROWS + r0 + rr]: 16B-contiguous segments per batch row
        const int t = threadIdx.x;
        if (t < 4 * BATCH) {
            const int b  = t >> 2;
            const int rr = t & 3;
            __builtin_nontemporal_store(tile[rr][b],
                                        dst32 + b * ROWS + blockIdx.x * 4 + rr);
        }
    }
}

extern "C" void kernel_launch(void* const* d_in, const int* in_sizes, int n_in,
                              void* d_out, int out_size, void* d_ws, size_t ws_size,
                              hipStream_t stream) {
    // setup_inputs order: x, a_idx, a_vals, b_idx, b_vals
    const float* x      = (const float*)d_in[0];   // [N, BATCH]
    const int*   a_idx  = (const int*)  d_in[1];   // [M, NNZ]
    const float* a_vals = (const float*)d_in[2];   // [M, NNZ]
    const int*   b_idx  = (const int*)  d_in[3];   // [K, NNZ]
    const float* b_vals = (const float*)d_in[4];   // [K, NNZ]
    float*       out    = (float*)d_out;           // [BATCH, M] fp32

    _Float16* bx16 = (_Float16*)d_ws;                        // 512 KB
    _Float16* x16  = (_Float16*)d_ws + (size_t)ROWS * BATCH; // 512 KB

    dim3 block(256);

    // Stage 0: convert x to fp16 (262144 elems, 4/thread)
    cvt_f32_f16<<<dim3(ROWS * BATCH / 4 / 256), block, 0, stream>>>(x, x16);
    // Stage 1: bx16 = B @ x
    ell_spmv_h<true ><<<dim3(ROWS / 4), block, 0, stream>>>(
        b_idx, b_vals, x16, bx16, nullptr);
    // Stage 2: out = A @ bx (transposed store)
    ell_spmv_h<false><<<dim3(ROWS / 4), block, 0, stream>>>(
        a_idx, a_vals, bx16, nullptr, out);
}